// Round 2
// baseline (274.712 us; speedup 1.0000x reference)
//
#include <hip/hip_runtime.h>
#include <hip/hip_bf16.h>

#define N_NODES 100000
#define DIM 64
#define SCAN_B 256

#define RANGE_NODES 50000   // node-range per histogram block (50KB LDS bytes)
#define HWORDS 12500        // RANGE_NODES/4 packed-byte words
#define HCHUNKS 64          // edge chunks per (array,range)
#define SCHUNKS 128         // edge chunks for bin scatter
#define BINSZ 512           // dst nodes per bin
#define NBINS 196           // ceil(N_NODES/BINSZ)

// ---------------------------------------------------------------------------
// Packed-byte histogram, one launch: blocks [0,128) = src, [128,256) = dst.
// Within each array: block = range*64 + chunk. No global atomics.
// ---------------------------------------------------------------------------
__global__ __launch_bounds__(256) void hist_kernel(
    const int* __restrict__ src, const int* __restrict__ dst, int nkeys,
    unsigned int* __restrict__ partials) {
  __shared__ unsigned int h[HWORDS];
  int which = blockIdx.x >> 7;             // 0 = src, 1 = dst
  int local = blockIdx.x & 127;
  int range = local >> 6;
  int chunk = local & 63;
  const int* keys = which ? dst : src;
  int lo = range * RANGE_NODES;
  for (int i = threadIdx.x; i < HWORDS; i += 256) h[i] = 0;
  __syncthreads();
  int per = (nkeys + HCHUNKS - 1) / HCHUNKS;
  int beg = chunk * per;
  int end = min(beg + per, nkeys);
  for (int i = beg + threadIdx.x; i < end; i += 256) {
    int k = keys[i] - lo;
    if ((unsigned)k < (unsigned)RANGE_NODES)
      atomicAdd(&h[k >> 2], 1u << ((k & 3) * 8));
  }
  __syncthreads();
  unsigned int* outp = partials + (size_t)blockIdx.x * HWORDS;
  for (int i = threadIdx.x; i < HWORDS; i += 256) outp[i] = h[i];
}

// ---------------------------------------------------------------------------
// Sum 64 chunk-partials per word, unpack bytes -> sn / dn / ideg.
// ---------------------------------------------------------------------------
__global__ __launch_bounds__(256) void reduce_norm_kernel(
    const unsigned int* __restrict__ ps, const unsigned int* __restrict__ pd,
    float* __restrict__ sn, float* __restrict__ dn, int* __restrict__ ideg) {
  int w = blockIdx.x * 256 + threadIdx.x;
  if (w >= 2 * (N_NODES / 4)) return;
  int is_dst = (w >= N_NODES / 4);
  int lw = is_dst ? w - N_NODES / 4 : w;
  const unsigned int* p = is_dst ? pd : ps;
  int r = lw / HWORDS, wr = lw % HWORDS;
  const unsigned int* base = p + (size_t)(r * HCHUNKS) * HWORDS + wr;
  unsigned int s0 = 0, s1 = 0, s2 = 0, s3 = 0;
  for (int c = 0; c < HCHUNKS; ++c) {
    unsigned int v = base[(size_t)c * HWORDS];
    s0 += v & 255u; s1 += (v >> 8) & 255u; s2 += (v >> 16) & 255u; s3 += v >> 24;
  }
  unsigned int d[4] = {s0, s1, s2, s3};
  int n0 = r * RANGE_NODES + wr * 4;
#pragma unroll
  for (int j = 0; j < 4; ++j) {
    int n = n0 + j;
    float f = (d[j] > 0) ? rsqrtf((float)d[j]) : 0.0f;
    if (is_dst) { dn[n] = f; ideg[n] = (int)d[j]; }
    else        { sn[n] = f; }
  }
}

// ---------------------------------------------------------------------------
// xb[n][k] = bf16( x[n][k] * sn[n] )  — prescaled bf16 gather operand.
// Thread handles 4 floats (row-aligned since DIM%4==0).
// ---------------------------------------------------------------------------
__global__ __launch_bounds__(256) void convert_prescale_kernel(
    const float* __restrict__ x, const float* __restrict__ sn,
    unsigned int* __restrict__ xb2, int nquads) {
  int i = blockIdx.x * 256 + threadIdx.x;
  if (i >= nquads) return;
  float s = sn[i >> 4];                       // node = (i*4)/64
  float4 v = ((const float4*)x)[i];
  __hip_bfloat162 a = __float22bfloat162_rn(make_float2(v.x * s, v.y * s));
  __hip_bfloat162 b = __float22bfloat162_rn(make_float2(v.z * s, v.w * s));
  unsigned int wa, wb;
  __builtin_memcpy(&wa, &a, 4);
  __builtin_memcpy(&wb, &b, 4);
  ((uint2*)xb2)[i] = make_uint2(wa, wb);
}

// ---------------------------------------------------------------------------
// Exclusive scan, 3-kernel classic (n = 100000, nb = 391).
// ---------------------------------------------------------------------------
__global__ __launch_bounds__(SCAN_B) void scan_block_kernel(
    const int* __restrict__ in, int* __restrict__ out,
    int* __restrict__ bsum, int n) {
  __shared__ int s[SCAN_B];
  int t = threadIdx.x;
  int i = blockIdx.x * SCAN_B + t;
  int v = (i < n) ? in[i] : 0;
  s[t] = v;
  __syncthreads();
  for (int off = 1; off < SCAN_B; off <<= 1) {
    int add = (t >= off) ? s[t - off] : 0;
    __syncthreads();
    s[t] += add;
    __syncthreads();
  }
  if (i < n) out[i] = s[t] - v;
  if (t == SCAN_B - 1) bsum[blockIdx.x] = s[t];
}

__global__ __launch_bounds__(512) void scan_top_kernel(
    int* __restrict__ bsum, int nb) {
  __shared__ int s[512];
  int t = threadIdx.x;
  int v = (t < nb) ? bsum[t] : 0;
  s[t] = v;
  __syncthreads();
  for (int off = 1; off < 512; off <<= 1) {
    int add = (t >= off) ? s[t - off] : 0;
    __syncthreads();
    s[t] += add;
    __syncthreads();
  }
  if (t < nb) bsum[t] = s[t] - v;
}

__global__ __launch_bounds__(256) void scan_add_kernel(
    int* __restrict__ out, const int* __restrict__ bsum, int n, int total) {
  int i = blockIdx.x * blockDim.x + threadIdx.x;
  if (i < n) out[i] += bsum[i / SCAN_B];
  if (i == 0) out[n] = total;
}

// ---------------------------------------------------------------------------
// Partition edges into NBINS dst-bins (LDS counts, 1 global atomic per
// (block,bin), LDS-ticket scatter into contiguous runs).
// ---------------------------------------------------------------------------
__global__ __launch_bounds__(256) void bin_scatter_kernel(
    const int* __restrict__ src, const int* __restrict__ dst,
    const int* __restrict__ offsets, int* __restrict__ bin_cursor,
    int2* __restrict__ binned, int E) {
  __shared__ int cnt[NBINS];
  __shared__ int base[NBINS];
  int t = threadIdx.x;
  for (int i = t; i < NBINS; i += 256) cnt[i] = 0;
  __syncthreads();
  int per = (E + SCHUNKS - 1) / SCHUNKS;
  int beg = blockIdx.x * per;
  int end = min(beg + per, E);
  for (int i = beg + t; i < end; i += 256)
    atomicAdd(&cnt[dst[i] >> 9], 1);
  __syncthreads();
  for (int i = t; i < NBINS; i += 256) {
    base[i] = offsets[i << 9] + atomicAdd(&bin_cursor[i], cnt[i]);
    cnt[i] = 0;
  }
  __syncthreads();
  for (int i = beg + t; i < end; i += 256) {
    int s = src[i], d = dst[i];
    int b = d >> 9;
    int r = atomicAdd(&cnt[b], 1);
    binned[base[b] + r] = make_int2(s, d);
  }
}

// ---------------------------------------------------------------------------
// CSR fill, one block per bin (LDS cursors, writes confined to bin window).
// ---------------------------------------------------------------------------
__global__ __launch_bounds__(256) void fill_binned_kernel(
    const int2* __restrict__ binned, const int* __restrict__ offsets,
    int* __restrict__ csr_src) {
  __shared__ int cur[BINSZ];
  __shared__ int offs[BINSZ];
  int b = blockIdx.x;
  int t = threadIdx.x;
  int lo = b << 9;
  for (int i = t; i < BINSZ; i += 256) {
    cur[i] = 0;
    offs[i] = offsets[min(lo + i, N_NODES)];
  }
  __syncthreads();
  int w0 = offsets[lo];
  int w1 = offsets[min(lo + BINSZ, N_NODES)];
  for (int e = w0 + t; e < w1; e += 256) {
    int2 sd = binned[e];
    int r = atomicAdd(&cur[sd.y - lo], 1);
    csr_src[offs[sd.y - lo] + r] = sd.x;
  }
}

// ---------------------------------------------------------------------------
// Fused layer v3: wave per dst node.
//   Gather: lane = (edge-sub-slot g = lane>>4, feature-quad q = lane&15);
//           each lane loads uint2 = 4 bf16 feats -> 4 edge rows per wave-load.
//   Reduce: 8 x shfl_xor (16,32) combines the 4 edge-sub-slot partials.
//   Project: W column PINNED in 64 VGPRs via empty inline-asm "+v" touch —
//            v2's plain array was sunk by the compiler into per-node global
//            reloads (VGPR_Count=56 < 64 proved it; ~64 VMEM/node on L1 path).
//            Row broadcast via 16 ds_read_b128.
// ---------------------------------------------------------------------------
__device__ __forceinline__ float bf_lo(unsigned int u) {
  unsigned int x = u << 16; float f; __builtin_memcpy(&f, &x, 4); return f;
}
__device__ __forceinline__ float bf_hi(unsigned int u) {
  unsigned int x = u & 0xffff0000u; float f; __builtin_memcpy(&f, &x, 4); return f;
}

template <bool PRESCALE, typename OUT_T>
__global__ __launch_bounds__(256, 4) void fused_layer_kernel(
    const __hip_bfloat16* __restrict__ xb, const int* __restrict__ csr_src,
    const int* __restrict__ offsets, const float* __restrict__ sn,
    const float* __restrict__ dn, const float* __restrict__ W,
    const float* __restrict__ bias, OUT_T* __restrict__ out, int N) {
  __shared__ __align__(16) float rowS[4][DIM];   // 1 KiB

  int t = threadIdx.x;
  int lane = t & 63;
  int wslot = t >> 6;
  int g = lane >> 4;           // edge sub-slot 0..3
  int q = lane & 15;           // feature quad: features 4q..4q+3

  // Per-lane W column (output feature c = lane), pinned in VGPRs.
  float wcol[DIM];
#pragma unroll
  for (int k = 0; k < DIM; ++k) wcol[k] = W[k * DIM + lane];
#pragma unroll
  for (int k = 0; k < DIM; ++k) asm volatile("" : "+v"(wcol[k]));  // pin
  float bcol = bias[lane];

  const uint2* __restrict__ xr = (const uint2*)xb;   // one row = 16 uint2
  int nwaves = gridDim.x * 4;

  for (int wid = blockIdx.x * 4 + wslot; wid < N; wid += nwaves) {
    int beg = offsets[wid];
    int end = offsets[wid + 1];

    float a0 = 0.f, a1 = 0.f, a2 = 0.f, a3 = 0.f;

    for (int base = beg; base < end; base += 16) {
      int j0 = base + g;
      int jm = end - 1;
      bool p0 = j0 < end, p1 = j0 + 4 < end, p2 = j0 + 8 < end,
           p3 = j0 + 12 < end;
      // clamped idx loads: all 4 issue unconditionally (addresses valid)
      int s0 = csr_src[min(j0, jm)];
      int s1 = csr_src[min(j0 + 4, jm)];
      int s2 = csr_src[min(j0 + 8, jm)];
      int s3 = csr_src[min(j0 + 12, jm)];
      // predicated row loads; default = bf16 zeros -> accumulate is unmasked
      uint2 v0 = make_uint2(0u, 0u), v1 = v0, v2 = v0, v3 = v0;
      if (p0) v0 = xr[(size_t)s0 * 16 + q];
      if (p1) v1 = xr[(size_t)s1 * 16 + q];
      if (p2) v2 = xr[(size_t)s2 * 16 + q];
      if (p3) v3 = xr[(size_t)s3 * 16 + q];
      a0 += bf_lo(v0.x); a1 += bf_hi(v0.x); a2 += bf_lo(v0.y); a3 += bf_hi(v0.y);
      a0 += bf_lo(v1.x); a1 += bf_hi(v1.x); a2 += bf_lo(v1.y); a3 += bf_hi(v1.y);
      a0 += bf_lo(v2.x); a1 += bf_hi(v2.x); a2 += bf_lo(v2.y); a3 += bf_hi(v2.y);
      a0 += bf_lo(v3.x); a1 += bf_hi(v3.x); a2 += bf_lo(v3.y); a3 += bf_hi(v3.y);
    }

    // combine the 4 edge-sub-slot partials (lanes differ in bits 4,5)
    a0 += __shfl_xor(a0, 16); a1 += __shfl_xor(a1, 16);
    a2 += __shfl_xor(a2, 16); a3 += __shfl_xor(a3, 16);
    a0 += __shfl_xor(a0, 32); a1 += __shfl_xor(a1, 32);
    a2 += __shfl_xor(a2, 32); a3 += __shfl_xor(a3, 32);

    float dnw = dn[wid];
    if (lane < 16)
      ((float4*)rowS[wslot])[lane] =
          make_float4(a0 * dnw, a1 * dnw, a2 * dnw, a3 * dnw);
    // same-wave LDS write -> read: ordered by lgkmcnt, no barrier needed
    const float4* r4 = (const float4*)rowS[wslot];
    float o0 = bcol, o1 = 0.f, o2 = 0.f, o3 = 0.f;
#pragma unroll
    for (int k4 = 0; k4 < 16; ++k4) {
      float4 r = r4[k4];
      o0 = fmaf(r.x, wcol[4 * k4 + 0], o0);
      o1 = fmaf(r.y, wcol[4 * k4 + 1], o1);
      o2 = fmaf(r.z, wcol[4 * k4 + 2], o2);
      o3 = fmaf(r.w, wcol[4 * k4 + 3], o3);
    }
    float o = fmaxf((o0 + o1) + (o2 + o3), 0.0f);
    if (PRESCALE) {
      out[(long)wid * DIM + lane] = (OUT_T)__float2bfloat16(o * sn[wid]);
    } else {
      out[(long)wid * DIM + lane] = (OUT_T)o;
    }
  }
}

extern "C" void kernel_launch(void* const* d_in, const int* in_sizes, int n_in,
                              void* d_out, int out_size, void* d_ws, size_t ws_size,
                              hipStream_t stream) {
  const float* x        = (const float*)d_in[0];
  const int*   edge_src = (const int*)d_in[1];
  const int*   edge_dst = (const int*)d_in[2];
  const float* W1       = (const float*)d_in[3];
  const float* b1       = (const float*)d_in[4];
  const float* W2       = (const float*)d_in[5];
  const float* b2       = (const float*)d_in[6];
  float* out = (float*)d_out;

  const int E = in_sizes[1];
  const int N = N_NODES;
  const int NB = (N + SCAN_B - 1) / SCAN_B;   // 391

  // Workspace (4B units), ~33.6 MB total. regionB time-shared:
  //   partials (hist..reduce) -> binned (bin_scatter..fill) -> h1b (layers)
  float* sn         = (float*)d_ws;                  // N
  float* dn         = sn + N;                        // N
  int*   ideg       = (int*)(dn + N);                // N
  int*   offsets    = ideg + N;                      // N+1
  int*   bsum       = offsets + (N + 1);             // 512
  int*   bin_cursor = bsum + 512;                    // 256
  int*   csr_src    = bin_cursor + 256;              // E
  unsigned int* xb_raw = (unsigned int*)(csr_src + E);       // N*DIM/2 (12.8MB)
  unsigned int* regionB = xb_raw + (size_t)N * DIM / 2;      // 12.8MB
  unsigned int* partials = regionB;                          // 256*HWORDS
  int2*  binned   = (int2*)regionB;                  // E int2
  __hip_bfloat16* xb  = (__hip_bfloat16*)xb_raw;
  __hip_bfloat16* h1b = (__hip_bfloat16*)regionB;

  hipMemsetAsync(bin_cursor, 0, 256 * sizeof(int), stream);

  // --- degrees + norms (no global atomics) ---
  hist_kernel<<<256, 256, 0, stream>>>(edge_src, edge_dst, E, partials);
  reduce_norm_kernel<<<(2 * (N / 4) + 255) / 256, 256, 0, stream>>>(
      partials, partials + (size_t)128 * HWORDS, sn, dn, ideg);

  // --- prescaled bf16 copy of x ---
  {
    int nquads = N * DIM / 4;
    convert_prescale_kernel<<<(nquads + 255) / 256, 256, 0, stream>>>(
        x, sn, xb_raw, nquads);
  }

  // --- offsets = exclusive scan of in-degree ---
  scan_block_kernel<<<NB, SCAN_B, 0, stream>>>(ideg, offsets, bsum, N);
  scan_top_kernel<<<1, 512, 0, stream>>>(bsum, NB);
  scan_add_kernel<<<(N + 255) / 256, 256, 0, stream>>>(offsets, bsum, N, E);

  // --- binned CSR build (overwrites partials region — dead after reduce) ---
  bin_scatter_kernel<<<SCHUNKS, 256, 0, stream>>>(edge_src, edge_dst, offsets,
                                                  bin_cursor, binned, E);
  fill_binned_kernel<<<NBINS, 256, 0, stream>>>(binned, offsets, csr_src);

  const int fb = 2048;   // grid-stride; 4 blocks/CU resident at ~128 VGPR

  // --- layer 1: xb -> h1b (bf16, prescaled by sn; overwrites binned) ---
  fused_layer_kernel<true, __hip_bfloat16><<<fb, 256, 0, stream>>>(
      xb, csr_src, offsets, sn, dn, W1, b1, h1b, N);

  // --- layer 2: h1b -> out (fp32) ---
  fused_layer_kernel<false, float><<<fb, 256, 0, stream>>>(
      h1b, csr_src, offsets, sn, dn, W2, b2, out, N);
}

// Round 3
// 274.420 us; speedup vs baseline: 1.0011x; 1.0011x over previous
//
#include <hip/hip_runtime.h>
#include <hip/hip_bf16.h>

#define N_NODES 100000
#define DIM 64
#define SCAN_B 256

#define RANGE_NODES 50000   // node-range per histogram block (50KB LDS bytes)
#define HWORDS 12500        // RANGE_NODES/4 packed-byte words
#define HCHUNKS 64          // edge chunks per (array,range)
#define SCHUNKS 128         // edge chunks for bin scatter
#define BINSZ 512           // dst nodes per bin
#define NBINS 196           // ceil(N_NODES/BINSZ)

// ---------------------------------------------------------------------------
// Packed-byte histogram, one launch: blocks [0,128) = src, [128,256) = dst.
// Within each array: block = range*64 + chunk. No global atomics.
// ---------------------------------------------------------------------------
__global__ __launch_bounds__(256) void hist_kernel(
    const int* __restrict__ src, const int* __restrict__ dst, int nkeys,
    unsigned int* __restrict__ partials) {
  __shared__ unsigned int h[HWORDS];
  int which = blockIdx.x >> 7;             // 0 = src, 1 = dst
  int local = blockIdx.x & 127;
  int range = local >> 6;
  int chunk = local & 63;
  const int* keys = which ? dst : src;
  int lo = range * RANGE_NODES;
  for (int i = threadIdx.x; i < HWORDS; i += 256) h[i] = 0;
  __syncthreads();
  int per = (nkeys + HCHUNKS - 1) / HCHUNKS;
  int beg = chunk * per;
  int end = min(beg + per, nkeys);
  for (int i = beg + threadIdx.x; i < end; i += 256) {
    int k = keys[i] - lo;
    if ((unsigned)k < (unsigned)RANGE_NODES)
      atomicAdd(&h[k >> 2], 1u << ((k & 3) * 8));
  }
  __syncthreads();
  unsigned int* outp = partials + (size_t)blockIdx.x * HWORDS;
  for (int i = threadIdx.x; i < HWORDS; i += 256) outp[i] = h[i];
}

// ---------------------------------------------------------------------------
// Sum 64 chunk-partials per word, unpack bytes -> sn / dn / ideg.
// ---------------------------------------------------------------------------
__global__ __launch_bounds__(256) void reduce_norm_kernel(
    const unsigned int* __restrict__ ps, const unsigned int* __restrict__ pd,
    float* __restrict__ sn, float* __restrict__ dn, int* __restrict__ ideg) {
  int w = blockIdx.x * 256 + threadIdx.x;
  if (w >= 2 * (N_NODES / 4)) return;
  int is_dst = (w >= N_NODES / 4);
  int lw = is_dst ? w - N_NODES / 4 : w;
  const unsigned int* p = is_dst ? pd : ps;
  int r = lw / HWORDS, wr = lw % HWORDS;
  const unsigned int* base = p + (size_t)(r * HCHUNKS) * HWORDS + wr;
  unsigned int s0 = 0, s1 = 0, s2 = 0, s3 = 0;
  for (int c = 0; c < HCHUNKS; ++c) {
    unsigned int v = base[(size_t)c * HWORDS];
    s0 += v & 255u; s1 += (v >> 8) & 255u; s2 += (v >> 16) & 255u; s3 += v >> 24;
  }
  unsigned int d[4] = {s0, s1, s2, s3};
  int n0 = r * RANGE_NODES + wr * 4;
#pragma unroll
  for (int j = 0; j < 4; ++j) {
    int n = n0 + j;
    float f = (d[j] > 0) ? rsqrtf((float)d[j]) : 0.0f;
    if (is_dst) { dn[n] = f; ideg[n] = (int)d[j]; }
    else        { sn[n] = f; }
  }
}

// ---------------------------------------------------------------------------
// xb[n][k] = bf16( x[n][k] * sn[n] )  — prescaled bf16 gather operand.
// Thread handles 4 floats (row-aligned since DIM%4==0).
// ---------------------------------------------------------------------------
__global__ __launch_bounds__(256) void convert_prescale_kernel(
    const float* __restrict__ x, const float* __restrict__ sn,
    unsigned int* __restrict__ xb2, int nquads) {
  int i = blockIdx.x * 256 + threadIdx.x;
  if (i >= nquads) return;
  float s = sn[i >> 4];                       // node = (i*4)/64
  float4 v = ((const float4*)x)[i];
  __hip_bfloat162 a = __float22bfloat162_rn(make_float2(v.x * s, v.y * s));
  __hip_bfloat162 b = __float22bfloat162_rn(make_float2(v.z * s, v.w * s));
  unsigned int wa, wb;
  __builtin_memcpy(&wa, &a, 4);
  __builtin_memcpy(&wb, &b, 4);
  ((uint2*)xb2)[i] = make_uint2(wa, wb);
}

// ---------------------------------------------------------------------------
// Exclusive scan, 3-kernel classic (n = 100000, nb = 391).
// ---------------------------------------------------------------------------
__global__ __launch_bounds__(SCAN_B) void scan_block_kernel(
    const int* __restrict__ in, int* __restrict__ out,
    int* __restrict__ bsum, int n) {
  __shared__ int s[SCAN_B];
  int t = threadIdx.x;
  int i = blockIdx.x * SCAN_B + t;
  int v = (i < n) ? in[i] : 0;
  s[t] = v;
  __syncthreads();
  for (int off = 1; off < SCAN_B; off <<= 1) {
    int add = (t >= off) ? s[t - off] : 0;
    __syncthreads();
    s[t] += add;
    __syncthreads();
  }
  if (i < n) out[i] = s[t] - v;
  if (t == SCAN_B - 1) bsum[blockIdx.x] = s[t];
}

__global__ __launch_bounds__(512) void scan_top_kernel(
    int* __restrict__ bsum, int nb) {
  __shared__ int s[512];
  int t = threadIdx.x;
  int v = (t < nb) ? bsum[t] : 0;
  s[t] = v;
  __syncthreads();
  for (int off = 1; off < 512; off <<= 1) {
    int add = (t >= off) ? s[t - off] : 0;
    __syncthreads();
    s[t] += add;
    __syncthreads();
  }
  if (t < nb) bsum[t] = s[t] - v;
}

__global__ __launch_bounds__(256) void scan_add_kernel(
    int* __restrict__ out, const int* __restrict__ bsum, int n, int total) {
  int i = blockIdx.x * blockDim.x + threadIdx.x;
  if (i < n) out[i] += bsum[i / SCAN_B];
  if (i == 0) out[n] = total;
}

// ---------------------------------------------------------------------------
// Partition edges into NBINS dst-bins (LDS counts, 1 global atomic per
// (block,bin), LDS-ticket scatter into contiguous runs).
// ---------------------------------------------------------------------------
__global__ __launch_bounds__(256) void bin_scatter_kernel(
    const int* __restrict__ src, const int* __restrict__ dst,
    const int* __restrict__ offsets, int* __restrict__ bin_cursor,
    int2* __restrict__ binned, int E) {
  __shared__ int cnt[NBINS];
  __shared__ int base[NBINS];
  int t = threadIdx.x;
  for (int i = t; i < NBINS; i += 256) cnt[i] = 0;
  __syncthreads();
  int per = (E + SCHUNKS - 1) / SCHUNKS;
  int beg = blockIdx.x * per;
  int end = min(beg + per, E);
  for (int i = beg + t; i < end; i += 256)
    atomicAdd(&cnt[dst[i] >> 9], 1);
  __syncthreads();
  for (int i = t; i < NBINS; i += 256) {
    base[i] = offsets[i << 9] + atomicAdd(&bin_cursor[i], cnt[i]);
    cnt[i] = 0;
  }
  __syncthreads();
  for (int i = beg + t; i < end; i += 256) {
    int s = src[i], d = dst[i];
    int b = d >> 9;
    int r = atomicAdd(&cnt[b], 1);
    binned[base[b] + r] = make_int2(s, d);
  }
}

// ---------------------------------------------------------------------------
// CSR fill, one block per bin (LDS cursors, writes confined to bin window).
// ---------------------------------------------------------------------------
__global__ __launch_bounds__(256) void fill_binned_kernel(
    const int2* __restrict__ binned, const int* __restrict__ offsets,
    int* __restrict__ csr_src) {
  __shared__ int cur[BINSZ];
  __shared__ int offs[BINSZ];
  int b = blockIdx.x;
  int t = threadIdx.x;
  int lo = b << 9;
  for (int i = t; i < BINSZ; i += 256) {
    cur[i] = 0;
    offs[i] = offsets[min(lo + i, N_NODES)];
  }
  __syncthreads();
  int w0 = offsets[lo];
  int w1 = offsets[min(lo + BINSZ, N_NODES)];
  for (int e = w0 + t; e < w1; e += 256) {
    int2 sd = binned[e];
    int r = atomicAdd(&cur[sd.y - lo], 1);
    csr_src[offs[sd.y - lo] + r] = sd.x;
  }
}

// ---------------------------------------------------------------------------
// Fused layer v4: wave per dst node.
//   Gather: lane = (edge-sub-slot g = lane>>4, feature-quad q = lane&15);
//           each lane loads uint2 = 4 bf16 feats -> 4 edge rows per wave-load.
//   Reduce: 8 x shfl_xor (16,32) combines the 4 edge-sub-slot partials.
//   Project: W column in 64 VGPRs. v3's pin failed because the allocator's
//            occupancy TARGET stayed at 8 waves/EU (64-VGPR budget) and it
//            spilled wcol to scratch (VGPR_Count=56 both rounds).
//            amdgpu_waves_per_eu(4,4) pins the target -> 128-VGPR budget.
// ---------------------------------------------------------------------------
__device__ __forceinline__ float bf_lo(unsigned int u) {
  unsigned int x = u << 16; float f; __builtin_memcpy(&f, &x, 4); return f;
}
__device__ __forceinline__ float bf_hi(unsigned int u) {
  unsigned int x = u & 0xffff0000u; float f; __builtin_memcpy(&f, &x, 4); return f;
}

template <bool PRESCALE, typename OUT_T>
__global__
__attribute__((amdgpu_flat_work_group_size(256, 256), amdgpu_waves_per_eu(4, 4)))
void fused_layer_kernel(
    const __hip_bfloat16* __restrict__ xb, const int* __restrict__ csr_src,
    const int* __restrict__ offsets, const float* __restrict__ sn,
    const float* __restrict__ dn, const float* __restrict__ W,
    const float* __restrict__ bias, OUT_T* __restrict__ out, int N) {
  __shared__ __align__(16) float rowS[4][DIM];   // 1 KiB

  int t = threadIdx.x;
  int lane = t & 63;
  int wslot = t >> 6;
  int g = lane >> 4;           // edge sub-slot 0..3
  int q = lane & 15;           // feature quad: features 4q..4q+3

  // Per-lane W column (output feature c = lane), pinned in VGPRs.
  float wcol[DIM];
#pragma unroll
  for (int k = 0; k < DIM; ++k) wcol[k] = W[k * DIM + lane];
#pragma unroll
  for (int k = 0; k < DIM; ++k) asm volatile("" : "+v"(wcol[k]));  // pin
  float bcol = bias[lane];

  const uint2* __restrict__ xr = (const uint2*)xb;   // one row = 16 uint2
  int nwaves = gridDim.x * 4;

  for (int wid = blockIdx.x * 4 + wslot; wid < N; wid += nwaves) {
    int beg = offsets[wid];
    int end = offsets[wid + 1];

    float a0 = 0.f, a1 = 0.f, a2 = 0.f, a3 = 0.f;

    for (int base = beg; base < end; base += 16) {
      int j0 = base + g;
      int jm = end - 1;
      bool p0 = j0 < end, p1 = j0 + 4 < end, p2 = j0 + 8 < end,
           p3 = j0 + 12 < end;
      // clamped idx loads: all 4 issue unconditionally (addresses valid)
      int s0 = csr_src[min(j0, jm)];
      int s1 = csr_src[min(j0 + 4, jm)];
      int s2 = csr_src[min(j0 + 8, jm)];
      int s3 = csr_src[min(j0 + 12, jm)];
      // predicated row loads; default = bf16 zeros -> accumulate is unmasked
      uint2 v0 = make_uint2(0u, 0u), v1 = v0, v2 = v0, v3 = v0;
      if (p0) v0 = xr[(size_t)s0 * 16 + q];
      if (p1) v1 = xr[(size_t)s1 * 16 + q];
      if (p2) v2 = xr[(size_t)s2 * 16 + q];
      if (p3) v3 = xr[(size_t)s3 * 16 + q];
      a0 += bf_lo(v0.x); a1 += bf_hi(v0.x); a2 += bf_lo(v0.y); a3 += bf_hi(v0.y);
      a0 += bf_lo(v1.x); a1 += bf_hi(v1.x); a2 += bf_lo(v1.y); a3 += bf_hi(v1.y);
      a0 += bf_lo(v2.x); a1 += bf_hi(v2.x); a2 += bf_lo(v2.y); a3 += bf_hi(v2.y);
      a0 += bf_lo(v3.x); a1 += bf_hi(v3.x); a2 += bf_lo(v3.y); a3 += bf_hi(v3.y);
    }

    // combine the 4 edge-sub-slot partials (lanes differ in bits 4,5)
    a0 += __shfl_xor(a0, 16); a1 += __shfl_xor(a1, 16);
    a2 += __shfl_xor(a2, 16); a3 += __shfl_xor(a3, 16);
    a0 += __shfl_xor(a0, 32); a1 += __shfl_xor(a1, 32);
    a2 += __shfl_xor(a2, 32); a3 += __shfl_xor(a3, 32);

    float dnw = dn[wid];
    if (lane < 16)
      ((float4*)rowS[wslot])[lane] =
          make_float4(a0 * dnw, a1 * dnw, a2 * dnw, a3 * dnw);
    // same-wave LDS write -> read: ordered by lgkmcnt, no barrier needed
    const float4* r4 = (const float4*)rowS[wslot];
    float o0 = bcol, o1 = 0.f, o2 = 0.f, o3 = 0.f;
#pragma unroll
    for (int k4 = 0; k4 < 16; ++k4) {
      float4 r = r4[k4];
      o0 = fmaf(r.x, wcol[4 * k4 + 0], o0);
      o1 = fmaf(r.y, wcol[4 * k4 + 1], o1);
      o2 = fmaf(r.z, wcol[4 * k4 + 2], o2);
      o3 = fmaf(r.w, wcol[4 * k4 + 3], o3);
    }
    float o = fmaxf((o0 + o1) + (o2 + o3), 0.0f);
    if (PRESCALE) {
      out[(long)wid * DIM + lane] = (OUT_T)__float2bfloat16(o * sn[wid]);
    } else {
      out[(long)wid * DIM + lane] = (OUT_T)o;
    }
  }
}

extern "C" void kernel_launch(void* const* d_in, const int* in_sizes, int n_in,
                              void* d_out, int out_size, void* d_ws, size_t ws_size,
                              hipStream_t stream) {
  const float* x        = (const float*)d_in[0];
  const int*   edge_src = (const int*)d_in[1];
  const int*   edge_dst = (const int*)d_in[2];
  const float* W1       = (const float*)d_in[3];
  const float* b1       = (const float*)d_in[4];
  const float* W2       = (const float*)d_in[5];
  const float* b2       = (const float*)d_in[6];
  float* out = (float*)d_out;

  const int E = in_sizes[1];
  const int N = N_NODES;
  const int NB = (N + SCAN_B - 1) / SCAN_B;   // 391

  // Workspace (4B units), ~33.6 MB total. regionB time-shared:
  //   partials (hist..reduce) -> binned (bin_scatter..fill) -> h1b (layers)
  float* sn         = (float*)d_ws;                  // N
  float* dn         = sn + N;                        // N
  int*   ideg       = (int*)(dn + N);                // N
  int*   offsets    = ideg + N;                      // N+1
  int*   bsum       = offsets + (N + 1);             // 512
  int*   bin_cursor = bsum + 512;                    // 256
  int*   csr_src    = bin_cursor + 256;              // E
  unsigned int* xb_raw = (unsigned int*)(csr_src + E);       // N*DIM/2 (12.8MB)
  unsigned int* regionB = xb_raw + (size_t)N * DIM / 2;      // 12.8MB
  unsigned int* partials = regionB;                          // 256*HWORDS
  int2*  binned   = (int2*)regionB;                  // E int2
  __hip_bfloat16* xb  = (__hip_bfloat16*)xb_raw;
  __hip_bfloat16* h1b = (__hip_bfloat16*)regionB;

  hipMemsetAsync(bin_cursor, 0, 256 * sizeof(int), stream);

  // --- degrees + norms (no global atomics) ---
  hist_kernel<<<256, 256, 0, stream>>>(edge_src, edge_dst, E, partials);
  reduce_norm_kernel<<<(2 * (N / 4) + 255) / 256, 256, 0, stream>>>(
      partials, partials + (size_t)128 * HWORDS, sn, dn, ideg);

  // --- prescaled bf16 copy of x ---
  {
    int nquads = N * DIM / 4;
    convert_prescale_kernel<<<(nquads + 255) / 256, 256, 0, stream>>>(
        x, sn, xb_raw, nquads);
  }

  // --- offsets = exclusive scan of in-degree ---
  scan_block_kernel<<<NB, SCAN_B, 0, stream>>>(ideg, offsets, bsum, N);
  scan_top_kernel<<<1, 512, 0, stream>>>(bsum, NB);
  scan_add_kernel<<<(N + 255) / 256, 256, 0, stream>>>(offsets, bsum, N, E);

  // --- binned CSR build (overwrites partials region — dead after reduce) ---
  bin_scatter_kernel<<<SCHUNKS, 256, 0, stream>>>(edge_src, edge_dst, offsets,
                                                  bin_cursor, binned, E);
  fill_binned_kernel<<<NBINS, 256, 0, stream>>>(binned, offsets, csr_src);

  const int fb = 2048;   // grid-stride; 4 blocks/CU resident at 128 VGPR

  // --- layer 1: xb -> h1b (bf16, prescaled by sn; overwrites binned) ---
  fused_layer_kernel<true, __hip_bfloat16><<<fb, 256, 0, stream>>>(
      xb, csr_src, offsets, sn, dn, W1, b1, h1b, N);

  // --- layer 2: h1b -> out (fp32) ---
  fused_layer_kernel<false, float><<<fb, 256, 0, stream>>>(
      h1b, csr_src, offsets, sn, dn, W2, b2, out, N);
}